// Round 1
// baseline (1020.522 us; speedup 1.0000x reference)
//
#include <hip/hip_runtime.h>

#define B_ 4
#define C_ 128
#define N_ 4096          // H*W = 64*64
#define NB6 (6 * N_)

// ---------------- neigh = relu(Wn(256x4) @ event[ch 0,1,4,5]) ----------------
__global__ __launch_bounds__(256) void k_neigh(const float* __restrict__ ev,
        const float* __restrict__ w, const float* __restrict__ bias,
        float* __restrict__ out) {
    int idx = blockIdx.x * 256 + threadIdx.x;        // B*256*N = 2^22 threads
    int n = idx & (N_ - 1);
    int o = (idx >> 12) & 255;
    int b = idx >> 20;
    const float* e = ev + (size_t)b * NB6;
    const float* wr = w + o * 4;
    float acc = bias[o] + wr[0]*e[n] + wr[1]*e[N_+n] + wr[2]*e[4*N_+n] + wr[3]*e[5*N_+n];
    out[((size_t)b*256 + o) * N_ + n] = fmaxf(acc, 0.f);
}

// ---------------- now_f = relu(Wn1(128x2) @ event[ch 2,3]) ----------------
__global__ __launch_bounds__(256) void k_nowf(const float* __restrict__ ev,
        const float* __restrict__ w, const float* __restrict__ bias,
        float* __restrict__ out) {
    int idx = blockIdx.x * 256 + threadIdx.x;        // B*128*N = 2^21 threads
    int n = idx & (N_ - 1);
    int o = (idx >> 12) & 127;
    int b = idx >> 19;
    const float* e = ev + (size_t)b * NB6;
    const float* wr = w + o * 2;
    float acc = bias[o] + wr[0]*e[2*N_+n] + wr[1]*e[3*N_+n];
    out[((size_t)b*C_ + o) * N_ + n] = fmaxf(acc, 0.f);
}

// ---------------- generic conv-GEMM: Y = relu(W(M x K) @ X(K x N) + b) ------
// grid (N/64, M/64, B); per-block 64x64 tile, K-chunks of 64.
__global__ __launch_bounds__(256) void k_conv(const float* __restrict__ X, long long xs,
        const float* __restrict__ W, const float* __restrict__ bias,
        float* __restrict__ Y, long long ys, int K) {
    __shared__ float Wl[64][65];   // [m][k], pad 65 -> conflict-free strided reads
    __shared__ float Xl[64][64];   // [k][n]
    int t = threadIdx.x;
    int nb = blockIdx.x, mb = blockIdx.y, b = blockIdx.z;
    const float* Xb = X + (size_t)b * xs + nb * 64;
    const float* Wb = W + (size_t)(mb * 64) * K;
    int tr = t >> 4, tc = t & 15;
    int m0 = tr * 4, n0 = tc * 4;
    float acc[4][4] = {};
    for (int kc = 0; kc < K; kc += 64) {
        #pragma unroll
        for (int p = 0; p < 4; ++p) {
            int row = tr + p * 16;       // 0..63
            int col = tc * 4;            // 0..60
            float4 wv = *(const float4*)(Wb + (size_t)row * K + kc + col);
            Wl[row][col+0] = wv.x; Wl[row][col+1] = wv.y;
            Wl[row][col+2] = wv.z; Wl[row][col+3] = wv.w;
            *(float4*)&Xl[row][col] = *(const float4*)(Xb + (size_t)(kc + row) * N_ + col);
        }
        __syncthreads();
        #pragma unroll 4
        for (int k = 0; k < 64; ++k) {
            float a0 = Wl[m0+0][k], a1 = Wl[m0+1][k], a2 = Wl[m0+2][k], a3 = Wl[m0+3][k];
            float4 xv = *(const float4*)&Xl[k][n0];
            acc[0][0] += a0*xv.x; acc[0][1] += a0*xv.y; acc[0][2] += a0*xv.z; acc[0][3] += a0*xv.w;
            acc[1][0] += a1*xv.x; acc[1][1] += a1*xv.y; acc[1][2] += a1*xv.z; acc[1][3] += a1*xv.w;
            acc[2][0] += a2*xv.x; acc[2][1] += a2*xv.y; acc[2][2] += a2*xv.z; acc[2][3] += a2*xv.w;
            acc[3][0] += a3*xv.x; acc[3][1] += a3*xv.y; acc[3][2] += a3*xv.z; acc[3][3] += a3*xv.w;
        }
        __syncthreads();
    }
    #pragma unroll
    for (int r = 0; r < 4; ++r) {
        int m = mb * 64 + m0 + r;
        float bs = bias[m];
        float4 o;
        o.x = fmaxf(acc[r][0] + bs, 0.f);
        o.y = fmaxf(acc[r][1] + bs, 0.f);
        o.z = fmaxf(acc[r][2] + bs, 0.f);
        o.w = fmaxf(acc[r][3] + bs, 0.f);
        *(float4*)(Y + (size_t)b * ys + (size_t)m * N_ + nb * 64 + n0) = o;
    }
}

// ---------------- flash attention + epilogue -------------------------------
// out[b,c,n] = 1e-4 * sum_m softmax_m(q[:,n].k[:,m]) * v[c,m] + now_val[b,c,n]
// grid (N/64, B), 256 threads. Q/K/V are (B, C, N) f32.
__global__ __launch_bounds__(256) void k_flash(const float* __restrict__ Q,
        const float* __restrict__ Kp, const float* __restrict__ V,
        const float* __restrict__ NV, float* __restrict__ out) {
    __shared__ float ql[C_][64];     // 32 KB
    __shared__ float kl[C_][64];     // 32 KB
    __shared__ float vl[C_][64];     // 32 KB
    __shared__ float sl[64][65];     // 16.6 KB, pad 65 -> row reads conflict-free
    __shared__ float pmax[4][64];
    int t = threadIdx.x;
    int nb = blockIdx.x, b = blockIdx.y;
    size_t bo = (size_t)b * C_ * N_;
    int tr = t >> 4, tc = t & 15;
    // stage Q tile (reused across all 64 m-tiles)
    #pragma unroll
    for (int p = 0; p < 8; ++p) {
        int c = tr + p * 16;
        *(float4*)&ql[c][tc*4] = *(const float4*)(Q + bo + (size_t)c * N_ + nb*64 + tc*4);
    }
    int nrow = t & 63;          // softmax/PV: this thread's query row
    int g = t >> 6;             // wave id: c-range [g*32, g*32+32)
    int c0 = g * 32;
    float m_run = -1e30f, l_run = 0.f;
    float o_acc[32];
    #pragma unroll
    for (int j = 0; j < 32; ++j) o_acc[j] = 0.f;

    for (int mt = 0; mt < N_/64; ++mt) {
        __syncthreads();   // protect kl/vl/sl from previous iteration (and ql on iter 0)
        #pragma unroll
        for (int p = 0; p < 8; ++p) {
            int c = tr + p * 16;
            *(float4*)&kl[c][tc*4] = *(const float4*)(Kp + bo + (size_t)c * N_ + mt*64 + tc*4);
            *(float4*)&vl[c][tc*4] = *(const float4*)(V  + bo + (size_t)c * N_ + mt*64 + tc*4);
        }
        __syncthreads();
        // S tile: s[n][m], this thread does n = tc*4+i, m = tr*4+j
        float sa[4][4] = {};
        #pragma unroll 4
        for (int c = 0; c < C_; ++c) {
            float4 qv = *(const float4*)&ql[c][tc*4];
            float4 kv = *(const float4*)&kl[c][tr*4];
            sa[0][0]+=qv.x*kv.x; sa[0][1]+=qv.x*kv.y; sa[0][2]+=qv.x*kv.z; sa[0][3]+=qv.x*kv.w;
            sa[1][0]+=qv.y*kv.x; sa[1][1]+=qv.y*kv.y; sa[1][2]+=qv.y*kv.z; sa[1][3]+=qv.y*kv.w;
            sa[2][0]+=qv.z*kv.x; sa[2][1]+=qv.z*kv.y; sa[2][2]+=qv.z*kv.z; sa[2][3]+=qv.z*kv.w;
            sa[3][0]+=qv.w*kv.x; sa[3][1]+=qv.w*kv.y; sa[3][2]+=qv.w*kv.z; sa[3][3]+=qv.w*kv.w;
        }
        #pragma unroll
        for (int i = 0; i < 4; ++i)
            #pragma unroll
            for (int j = 0; j < 4; ++j)
                sl[tc*4+i][tr*4+j] = sa[i][j];
        __syncthreads();
        // partial row max (4 threads per row)
        float px = -1e30f;
        #pragma unroll
        for (int j = 0; j < 16; ++j) px = fmaxf(px, sl[nrow][g*16+j]);
        pmax[g][nrow] = px;
        __syncthreads();
        float tm = fmaxf(fmaxf(pmax[0][nrow], pmax[1][nrow]),
                         fmaxf(pmax[2][nrow], pmax[3][nrow]));
        float m_new = fmaxf(m_run, tm);
        float scale = __expf(m_run - m_new);
        l_run *= scale;
        #pragma unroll
        for (int j = 0; j < 32; ++j) o_acc[j] *= scale;
        m_run = m_new;
        // p row in registers (fully unrolled -> static indices)
        float pr[64];
        #pragma unroll
        for (int m = 0; m < 64; ++m) {
            float pv = __expf(sl[nrow][m] - m_new);
            pr[m] = pv;
            l_run += pv;
        }
        // PV: o_acc[j] += sum_m pr[m] * v[c0+j][m]   (float4 broadcast reads)
        #pragma unroll
        for (int j = 0; j < 32; ++j) {
            const float4* vrow = (const float4*)&vl[c0 + j][0];
            float s0 = 0.f, s1 = 0.f, s2 = 0.f, s3 = 0.f;
            #pragma unroll
            for (int q4 = 0; q4 < 16; ++q4) {
                float4 vv = vrow[q4];
                s0 += pr[q4*4+0] * vv.x;
                s1 += pr[q4*4+1] * vv.y;
                s2 += pr[q4*4+2] * vv.z;
                s3 += pr[q4*4+3] * vv.w;
            }
            o_acc[j] += (s0 + s1) + (s2 + s3);
        }
    }
    float inv = 1.f / l_run;
    #pragma unroll
    for (int j = 0; j < 32; ++j) {
        size_t oi = bo + (size_t)(c0 + j) * N_ + nb*64 + nrow;
        out[oi] = 1e-4f * (o_acc[j] * inv) + NV[oi];
    }
}

extern "C" void kernel_launch(void* const* d_in, const int* in_sizes, int n_in,
                              void* d_out, int out_size, void* d_ws, size_t ws_size,
                              hipStream_t stream) {
    const float* ev   = (const float*)d_in[0];
    const float* w_nb = (const float*)d_in[1];  const float* b_nb = (const float*)d_in[2];
    const float* w_pk = (const float*)d_in[3];  const float* b_pk = (const float*)d_in[4];
    const float* w_pv = (const float*)d_in[5];  const float* b_pv = (const float*)d_in[6];
    const float* w_lk = (const float*)d_in[7];  const float* b_lk = (const float*)d_in[8];
    const float* w_lv = (const float*)d_in[9];  const float* b_lv = (const float*)d_in[10];
    const float* w_t1 = (const float*)d_in[11]; const float* b_t1 = (const float*)d_in[12];
    const float* w_n1 = (const float*)d_in[13]; const float* b_n1 = (const float*)d_in[14];
    const float* w_nk = (const float*)d_in[15]; const float* b_nk = (const float*)d_in[16];
    const float* w_nv = (const float*)d_in[17]; const float* b_nv = (const float*)d_in[18];
    const float* w_q  = (const float*)d_in[19]; const float* b_q  = (const float*)d_in[20];
    const float* w_k  = (const float*)d_in[21]; const float* b_k  = (const float*)d_in[22];
    const float* w_v  = (const float*)d_in[23]; const float* b_v  = (const float*)d_in[24];

    float* ws = (float*)d_ws;
    const size_t SZ2 = (size_t)B_ * 256 * N_;   // 4,194,304 floats (16 MB)
    const size_t SZ1 = (size_t)B_ * C_  * N_;   // 2,097,152 floats ( 8 MB)
    // ws footprint: 3*SZ2 + 5*SZ1 = ~92 MB
    float* neigh = ws;            // (B,256,N): [pro-half | lat-half]
    float* kcat  = neigh + SZ2;   // (B,256,N): [pro_key ; lat_key]
    float* vcat  = kcat  + SZ2;   // (B,256,N): [pro_val ; lat_val]
    float* keyn  = vcat  + SZ2;   // (B,128,N)
    float* valn  = keyn  + SZ1;
    float* nowf  = valn  + SZ1;
    float* nowk  = nowf  + SZ1;
    float* nowv  = nowk  + SZ1;
    float* qb = neigh;            // reuse: neigh dead after pv/lv
    float* kb = kcat;             // reuse: kcat dead after keyn
    float* vb = vcat;             // reuse: vcat dead after valn
    const long long s2 = 256LL * N_;   // per-batch stride, 256-channel bufs
    const long long s1 = (long long)C_ * N_;

    k_neigh<<<dim3((B_*256*N_)/256), dim3(256), 0, stream>>>(ev, w_nb, b_nb, neigh);
    k_nowf <<<dim3((B_*C_ *N_)/256), dim3(256), 0, stream>>>(ev, w_n1, b_n1, nowf);

    dim3 g(N_/64, 2, B_), blk(256);
    k_conv<<<g, blk, 0, stream>>>(neigh,      s2, w_pk, b_pk, kcat,      s2, C_);
    k_conv<<<g, blk, 0, stream>>>(neigh,      s2, w_lk, b_lk, kcat + s1, s2, C_);
    k_conv<<<g, blk, 0, stream>>>(neigh + s1, s2, w_pv, b_pv, vcat,      s2, C_);
    k_conv<<<g, blk, 0, stream>>>(neigh + s1, s2, w_lv, b_lv, vcat + s1, s2, C_);
    k_conv<<<g, blk, 0, stream>>>(kcat, s2, w_t1, b_t1, keyn, s1, 256);
    k_conv<<<g, blk, 0, stream>>>(vcat, s2, w_t1, b_t1, valn, s1, 256);
    k_conv<<<g, blk, 0, stream>>>(nowf, s1, w_nk, b_nk, nowk, s1, C_);
    k_conv<<<g, blk, 0, stream>>>(nowf, s1, w_nv, b_nv, nowv, s1, C_);
    k_conv<<<g, blk, 0, stream>>>(keyn, s1, w_q,  b_q,  qb,   s1, C_);
    k_conv<<<g, blk, 0, stream>>>(nowk, s1, w_k,  b_k,  kb,   s1, C_);
    k_conv<<<g, blk, 0, stream>>>(valn, s1, w_v,  b_v,  vb,   s1, C_);

    k_flash<<<dim3(N_/64, B_), blk, 0, stream>>>(qb, kb, vb, nowv, (float*)d_out);
}

// Round 2
// 212.877 us; speedup vs baseline: 4.7940x; 4.7940x over previous
//
#include <hip/hip_runtime.h>

#define B_ 4
#define C_ 128
#define N_ 4096          // H*W = 64*64
#define NB6 (6 * N_)

typedef __attribute__((ext_vector_type(8))) __bf16 bf16x8;
typedef __attribute__((ext_vector_type(16))) float f32x16;

__device__ inline unsigned pk2(float lo, float hi) {
    unsigned short a = __builtin_bit_cast(unsigned short, (__bf16)lo);
    unsigned short b = __builtin_bit_cast(unsigned short, (__bf16)hi);
    return (unsigned)a | ((unsigned)b << 16);
}

__device__ inline void gload_lds16(const void* g, void* l) {
    __builtin_amdgcn_global_load_lds(
        (const __attribute__((address_space(1))) unsigned int*)g,
        (__attribute__((address_space(3))) unsigned int*)l, 16, 0, 0);
}

// ---------------- neigh = relu(Wn(256x4) @ event[ch 0,1,4,5]) ----------------
__global__ __launch_bounds__(256) void k_neigh(const float* __restrict__ ev,
        const float* __restrict__ w, const float* __restrict__ bias,
        float* __restrict__ out) {
    int idx = blockIdx.x * 256 + threadIdx.x;
    int n = idx & (N_ - 1);
    int o = (idx >> 12) & 255;
    int b = idx >> 20;
    const float* e = ev + (size_t)b * NB6;
    const float* wr = w + o * 4;
    float acc = bias[o] + wr[0]*e[n] + wr[1]*e[N_+n] + wr[2]*e[4*N_+n] + wr[3]*e[5*N_+n];
    out[((size_t)b*256 + o) * N_ + n] = fmaxf(acc, 0.f);
}

// ---------------- now_f = relu(Wn1(128x2) @ event[ch 2,3]) ----------------
__global__ __launch_bounds__(256) void k_nowf(const float* __restrict__ ev,
        const float* __restrict__ w, const float* __restrict__ bias,
        float* __restrict__ out) {
    int idx = blockIdx.x * 256 + threadIdx.x;
    int n = idx & (N_ - 1);
    int o = (idx >> 12) & 127;
    int b = idx >> 19;
    const float* e = ev + (size_t)b * NB6;
    const float* wr = w + o * 2;
    float acc = bias[o] + wr[0]*e[2*N_+n] + wr[1]*e[3*N_+n];
    out[((size_t)b*C_ + o) * N_ + n] = fmaxf(acc, 0.f);
}

// ---------------- generic conv-GEMM: Y = relu(W(M x K) @ X(K x N) + b) ------
// OM=0: f32 out (B,*,N). OM=1: bf16 out TRANSPOSED (B,N,C). OM=2: bf16 out (B,C,N).
template<int OM>
__global__ __launch_bounds__(256) void k_conv(const float* __restrict__ X, long long xs,
        const float* __restrict__ W, const float* __restrict__ bias,
        void* __restrict__ Yv, long long ys, int K) {
    __shared__ float Wl[64][65];
    __shared__ float Xl[64][64];
    int t = threadIdx.x;
    int nb = blockIdx.x, mb = blockIdx.y, b = blockIdx.z;
    const float* Xb = X + (size_t)b * xs + nb * 64;
    const float* Wb = W + (size_t)(mb * 64) * K;
    int tr = t >> 4, tc = t & 15;
    int m0 = tr * 4, n0 = tc * 4;
    float acc[4][4] = {};
    for (int kc = 0; kc < K; kc += 64) {
        #pragma unroll
        for (int p = 0; p < 4; ++p) {
            int row = tr + p * 16;
            int col = tc * 4;
            float4 wv = *(const float4*)(Wb + (size_t)row * K + kc + col);
            Wl[row][col+0] = wv.x; Wl[row][col+1] = wv.y;
            Wl[row][col+2] = wv.z; Wl[row][col+3] = wv.w;
            *(float4*)&Xl[row][col] = *(const float4*)(Xb + (size_t)(kc + row) * N_ + col);
        }
        __syncthreads();
        #pragma unroll 4
        for (int k = 0; k < 64; ++k) {
            float a0 = Wl[m0+0][k], a1 = Wl[m0+1][k], a2 = Wl[m0+2][k], a3 = Wl[m0+3][k];
            float4 xv = *(const float4*)&Xl[k][n0];
            acc[0][0] += a0*xv.x; acc[0][1] += a0*xv.y; acc[0][2] += a0*xv.z; acc[0][3] += a0*xv.w;
            acc[1][0] += a1*xv.x; acc[1][1] += a1*xv.y; acc[1][2] += a1*xv.z; acc[1][3] += a1*xv.w;
            acc[2][0] += a2*xv.x; acc[2][1] += a2*xv.y; acc[2][2] += a2*xv.z; acc[2][3] += a2*xv.w;
            acc[3][0] += a3*xv.x; acc[3][1] += a3*xv.y; acc[3][2] += a3*xv.z; acc[3][3] += a3*xv.w;
        }
        __syncthreads();
    }
    // bias + relu
    #pragma unroll
    for (int r = 0; r < 4; ++r) {
        float bs = bias[mb*64 + m0 + r];
        #pragma unroll
        for (int i = 0; i < 4; ++i) acc[r][i] = fmaxf(acc[r][i] + bs, 0.f);
    }
    if (OM == 0) {
        float* Y = (float*)Yv;
        #pragma unroll
        for (int r = 0; r < 4; ++r) {
            int m = mb * 64 + m0 + r;
            float4 o; o.x = acc[r][0]; o.y = acc[r][1]; o.z = acc[r][2]; o.w = acc[r][3];
            *(float4*)(Y + (size_t)b * ys + (size_t)m * N_ + nb * 64 + n0) = o;
        }
    } else if (OM == 2) {
        unsigned short* Y = (unsigned short*)Yv;
        #pragma unroll
        for (int r = 0; r < 4; ++r) {
            int m = mb * 64 + m0 + r;
            uint2 o; o.x = pk2(acc[r][0], acc[r][1]); o.y = pk2(acc[r][2], acc[r][3]);
            *(uint2*)(Y + (size_t)b * ys + (size_t)m * N_ + nb * 64 + n0) = o;
        }
    } else {
        // bf16 transposed: Y[b][n][c], tile rows n = nb*64.., cols c = mb*64..
        __shared__ unsigned short ldsT[64][68];
        #pragma unroll
        for (int i = 0; i < 4; ++i) {
            uint2 o; o.x = pk2(acc[0][i], acc[1][i]); o.y = pk2(acc[2][i], acc[3][i]);
            *(uint2*)&ldsT[n0 + i][m0] = o;
        }
        __syncthreads();
        int n_loc = t >> 2, ch = t & 3;
        const uint2* rp = (const uint2*)&ldsT[n_loc][ch * 16];
        uint2 r0 = rp[0], r1 = rp[1], r2 = rp[2], r3 = rp[3];
        unsigned short* Y = (unsigned short*)Yv;
        size_t gi = (size_t)b * ys + (size_t)(nb*64 + n_loc) * C_ + mb*64 + ch*16;
        uint4 g0; g0.x = r0.x; g0.y = r0.y; g0.z = r1.x; g0.w = r1.y;
        uint4 g1; g1.x = r2.x; g1.y = r2.y; g1.z = r3.x; g1.w = r3.y;
        *(uint4*)(Y + gi) = g0;
        *(uint4*)(Y + gi + 8) = g1;
    }
}

// ---------------- MFMA flash attention + epilogue ---------------------------
// Qt,Kt: (B,N,C) bf16 transposed; Vb: (B,C,N) bf16; NV,out: (B,C,N) f32.
// grid (N/64, B), 512 threads = 8 waves: nh=w&1 (n-half), mp=w>>1 (4-way m-split).
#define MT 32
#define NMT (N_ / MT)      // 128 m-tiles
#define SPLIT 4

__global__ __launch_bounds__(512, 2) void k_flash(
        const unsigned short* __restrict__ Qt, const unsigned short* __restrict__ Kt,
        const unsigned short* __restrict__ Vb, const float* __restrict__ NV,
        float* __restrict__ out) {
    __shared__ char stg[131072];                   // 4 mp-groups x dbuf x (K 8KB + V 8KB)
    __shared__ float cmb[2][SPLIT][2][32];
    const int t = threadIdx.x;
    const int lane = t & 63;
    const int w = t >> 6;
    const int nh = w & 1, mp = w >> 1;
    const int h = lane >> 5, nl = lane & 31;
    const int b = blockIdx.y;
    const int n0 = blockIdx.x * 64 + nh * 32;
    const size_t bo = (size_t)b * N_ * C_;

    // Q B-frags (hoisted): B[k=c][n] -> qf[kk], c = kk*16 + 8h + j, from Qt row (n0+nl)
    bf16x8 qf[8];
    {
        const char* qb = (const char*)(Qt + bo);
        #pragma unroll
        for (int kk = 0; kk < 8; ++kk)
            qf[kk] = *(const bf16x8*)(qb + (size_t)(n0 + nl) * 256 + kk*32 + h*16);
    }

    const char* ktb = (const char*)(Kt + bo);
    const char* vbb = (const char*)(Vb + bo);

    // accumulators: out rows c = 32*s + (r&3)+8*(r>>2)+4h, col n = nl
    f32x16 oa[4];
    #pragma unroll
    for (int s = 0; s < 4; ++s)
        #pragma unroll
        for (int r = 0; r < 16; ++r) oa[s][r] = 0.f;
    float m_run = -1e30f, l_run = 0.f;

    const int swzK = (nl & 15) << 4;
    const int swzV = ((nl >> 1) & 7) << 4;

    // staging: group mp stages its tile; nh=0 -> K (8KB), nh=1 -> V (8KB)
    auto stage = [&](int tile, int ph) {
        char* base = stg + (mp*2 + ph) * 16384;
        if (nh == 0) {
            const char* src = ktb + (size_t)tile * MT * 256;
            #pragma unroll
            for (int ii = 0; ii < 8; ++ii) {
                int L = ii*1024 + lane*16;
                int T = L ^ (((L >> 8) & 15) << 4);
                gload_lds16(src + T, base + ii*1024);
            }
        } else {
            const char* src = vbb + (size_t)tile * MT * 2;   // column offset in V row
            #pragma unroll
            for (int ii = 0; ii < 8; ++ii) {
                int L = ii*1024 + lane*16;
                int T = L ^ (((L >> 7) & 7) << 4);
                int c = T >> 6, inner = T & 63;
                gload_lds16(src + (size_t)c * (N_*2) + inner, base + 8192 + ii*1024);
            }
        }
    };

    stage(mp, 0);
    asm volatile("s_waitcnt vmcnt(0)" ::: "memory");
    __syncthreads();

    for (int it = 0; it < NMT / SPLIT; ++it) {     // 32 iterations
        int ph = it & 1;
        if (it + 1 < NMT / SPLIT) stage((it + 1) * SPLIT + mp, ph ^ 1);
        const char* kb = stg + (mp*2 + ph) * 16384;
        const char* vb = kb + 8192;

        // S^T tile (32m x 32n) = Kt_tile(32m x 128c) * Q(128c x 32n)
        f32x16 s;
        #pragma unroll
        for (int r = 0; r < 16; ++r) s[r] = 0.f;
        #pragma unroll
        for (int kk = 0; kk < 8; ++kk) {
            int y = nl*256 + kk*32 + h*16;
            bf16x8 a = *(const bf16x8*)(kb + (y ^ swzK));
            s = __builtin_amdgcn_mfma_f32_32x32x16_bf16(a, qf[kk], s, 0, 0, 0);
        }

        // online softmax over m (per lane: 16 m-values for its n)
        float tm = -1e30f;
        #pragma unroll
        for (int r = 0; r < 16; ++r) tm = fmaxf(tm, s[r]);
        tm = fmaxf(tm, __shfl_xor(tm, 32));
        float mn = fmaxf(m_run, tm);
        float sc = __expf(m_run - mn);
        m_run = mn;
        float p[16];
        float ls = 0.f;
        #pragma unroll
        for (int r = 0; r < 16; ++r) { p[r] = __expf(s[r] - mn); ls += p[r]; }
        ls += __shfl_xor(ls, 32);
        l_run = l_run * sc + ls;
        #pragma unroll
        for (int ss = 0; ss < 4; ++ss)
            #pragma unroll
            for (int r = 0; r < 16; ++r) oa[ss][r] *= sc;

        // pack P to bf16 pairs; exchange across wave halves
        unsigned pk[8], opk[8];
        #pragma unroll
        for (int q = 0; q < 8; ++q) pk[q] = pk2(p[2*q], p[2*q+1]);
        #pragma unroll
        for (int q = 0; q < 8; ++q) opk[q] = (unsigned)__shfl_xor((int)pk[q], 32);

        // PV: oa[s] += V(32c x 16m) * P(16m x 32n), 2 k-steps
        #pragma unroll
        for (int kk2 = 0; kk2 < 2; ++kk2) {
            unsigned w0 = h ? opk[4*kk2+2] : pk [4*kk2+0];
            unsigned w1 = h ? opk[4*kk2+3] : pk [4*kk2+1];
            unsigned w2 = h ? pk [4*kk2+2] : opk[4*kk2+0];
            unsigned w3 = h ? pk [4*kk2+3] : opk[4*kk2+1];
            typedef __attribute__((ext_vector_type(4))) unsigned u32x4;
            u32x4 uw = {w0, w1, w2, w3};
            bf16x8 pf = __builtin_bit_cast(bf16x8, uw);
            #pragma unroll
            for (int ss = 0; ss < 4; ++ss) {
                int y = (32*ss + nl)*64 + kk2*32 + h*16;
                bf16x8 va = *(const bf16x8*)(vb + (y ^ swzV));
                oa[ss] = __builtin_amdgcn_mfma_f32_32x32x16_bf16(va, pf, oa[ss], 0, 0, 0);
            }
        }

        asm volatile("s_waitcnt vmcnt(0)" ::: "memory");
        __syncthreads();
    }

    // -------- combine 4-way m-split --------
    if (h == 0) { cmb[nh][mp][0][nl] = m_run; cmb[nh][mp][1][nl] = l_run; }
    __syncthreads();
    float M = -1e30f;
    #pragma unroll
    for (int j = 0; j < SPLIT; ++j) M = fmaxf(M, cmb[nh][j][0][nl]);
    float lt = 0.f;
    #pragma unroll
    for (int j = 0; j < SPLIT; ++j) lt += cmb[nh][j][1][nl] * __expf(cmb[nh][j][0][nl] - M);
    float aw = __expf(m_run - M);
    float* osc = (float*)stg;   // [(mp-1)*2+nh][128c][32n] f32, 96 KB
    if (mp != 0) {
        float* dst = osc + (size_t)((mp-1)*2 + nh) * 4096;
        #pragma unroll
        for (int ss = 0; ss < 4; ++ss)
            #pragma unroll
            for (int r = 0; r < 16; ++r) {
                int c = 32*ss + (r&3) + 8*(r>>2) + 4*h;
                dst[c*32 + nl] = oa[ss][r] * aw;
            }
    }
    __syncthreads();
    if (mp == 0) {
        const float* nvb = NV + bo;
        float* ob = out + bo;
        float inv = 1.f / lt;
        #pragma unroll
        for (int ss = 0; ss < 4; ++ss)
            #pragma unroll
            for (int r = 0; r < 16; ++r) {
                int c = 32*ss + (r&3) + 8*(r>>2) + 4*h;
                float v = oa[ss][r] * aw;
                v += osc[0*8192/2 + (0*2+nh)*4096 + c*32 + nl];
                v += osc[(1*2+nh)*4096 + c*32 + nl];
                v += osc[(2*2+nh)*4096 + c*32 + nl];
                size_t gi = (size_t)c * N_ + blockIdx.x*64 + nh*32 + nl;
                ob[gi] = 1e-4f * (v * inv) + nvb[gi];
            }
    }
}

extern "C" void kernel_launch(void* const* d_in, const int* in_sizes, int n_in,
                              void* d_out, int out_size, void* d_ws, size_t ws_size,
                              hipStream_t stream) {
    const float* ev   = (const float*)d_in[0];
    const float* w_nb = (const float*)d_in[1];  const float* b_nb = (const float*)d_in[2];
    const float* w_pk = (const float*)d_in[3];  const float* b_pk = (const float*)d_in[4];
    const float* w_pv = (const float*)d_in[5];  const float* b_pv = (const float*)d_in[6];
    const float* w_lk = (const float*)d_in[7];  const float* b_lk = (const float*)d_in[8];
    const float* w_lv = (const float*)d_in[9];  const float* b_lv = (const float*)d_in[10];
    const float* w_t1 = (const float*)d_in[11]; const float* b_t1 = (const float*)d_in[12];
    const float* w_n1 = (const float*)d_in[13]; const float* b_n1 = (const float*)d_in[14];
    const float* w_nk = (const float*)d_in[15]; const float* b_nk = (const float*)d_in[16];
    const float* w_nv = (const float*)d_in[17]; const float* b_nv = (const float*)d_in[18];
    const float* w_q  = (const float*)d_in[19]; const float* b_q  = (const float*)d_in[20];
    const float* w_k  = (const float*)d_in[21]; const float* b_k  = (const float*)d_in[22];
    const float* w_v  = (const float*)d_in[23]; const float* b_v  = (const float*)d_in[24];

    float* ws = (float*)d_ws;
    const size_t SZ2 = (size_t)B_ * 256 * N_;   // 16 MB (floats)
    const size_t SZ1 = (size_t)B_ * C_  * N_;   // 8 MB
    float* neigh = ws;
    float* kcat  = neigh + SZ2;
    float* vcat  = kcat  + SZ2;
    float* keyn  = vcat  + SZ2;
    float* valn  = keyn  + SZ1;
    float* nowf  = valn  + SZ1;
    float* nowk  = nowf  + SZ1;
    float* nowv  = nowk  + SZ1;
    // bf16 buffers reuse dead f32 regions
    unsigned short* Qt = (unsigned short*)neigh;  // (B,N,C) bf16, 4MB
    unsigned short* Kb = (unsigned short*)kcat;   // (B,N,C) bf16
    unsigned short* Vb = (unsigned short*)vcat;   // (B,C,N) bf16
    const long long s2 = 256LL * N_;
    const long long s1 = (long long)C_ * N_;
    const long long st = (long long)N_ * C_;

    k_neigh<<<dim3((B_*256*N_)/256), dim3(256), 0, stream>>>(ev, w_nb, b_nb, neigh);
    k_nowf <<<dim3((B_*C_ *N_)/256), dim3(256), 0, stream>>>(ev, w_n1, b_n1, nowf);

    dim3 g(N_/64, 2, B_), blk(256);
    k_conv<0><<<g, blk, 0, stream>>>(neigh,      s2, w_pk, b_pk, kcat,      s2, C_);
    k_conv<0><<<g, blk, 0, stream>>>(neigh,      s2, w_lk, b_lk, kcat + s1, s2, C_);
    k_conv<0><<<g, blk, 0, stream>>>(neigh + s1, s2, w_pv, b_pv, vcat,      s2, C_);
    k_conv<0><<<g, blk, 0, stream>>>(neigh + s1, s2, w_lv, b_lv, vcat + s1, s2, C_);
    k_conv<0><<<g, blk, 0, stream>>>(kcat, s2, w_t1, b_t1, keyn, s1, 256);
    k_conv<0><<<g, blk, 0, stream>>>(vcat, s2, w_t1, b_t1, valn, s1, 256);
    k_conv<0><<<g, blk, 0, stream>>>(nowf, s1, w_nk, b_nk, nowk, s1, C_);
    k_conv<0><<<g, blk, 0, stream>>>(nowf, s1, w_nv, b_nv, nowv, s1, C_);
    k_conv<1><<<g, blk, 0, stream>>>(keyn, s1, w_q,  b_q,  Qt,   st, C_);
    k_conv<1><<<g, blk, 0, stream>>>(nowk, s1, w_k,  b_k,  Kb,   st, C_);
    k_conv<2><<<g, blk, 0, stream>>>(valn, s1, w_v,  b_v,  Vb,   s1, C_);

    k_flash<<<dim3(N_/64, B_), dim3(512), 0, stream>>>(Qt, Kb, Vb, nowv, (float*)d_out);
}

// Round 3
// 110.845 us; speedup vs baseline: 9.2068x; 1.9205x over previous
//
#include <hip/hip_runtime.h>

#define B_ 4
#define C_ 128
#define N_ 4096          // H*W = 64*64

typedef __attribute__((ext_vector_type(8))) __bf16 bf16x8;
typedef __attribute__((ext_vector_type(16))) float f32x16;

#define SWZ(n) (((n) & 15) << 4)

__device__ __forceinline__ unsigned short cvb(float x) {
    return __builtin_bit_cast(unsigned short, (__bf16)x);
}
__device__ __forceinline__ unsigned pk2(float lo, float hi) {
    return (unsigned)cvb(lo) | ((unsigned)cvb(hi) << 16);
}
__device__ inline void gload_lds16(const void* g, void* l) {
    __builtin_amdgcn_global_load_lds(
        (const __attribute__((address_space(1))) unsigned int*)g,
        (__attribute__((address_space(3))) unsigned int*)l, 16, 0, 0);
}

// ============ weight convert f32 -> bf16 (row-major, concat) ============
__global__ __launch_bounds__(256) void k_wcvt(
        const float* pk, const float* lk, const float* pv, const float* lv,
        const float* t1, const float* nk, const float* nv,
        const float* q, const float* k, const float* v,
        const float* bpk, const float* blk, const float* bpv, const float* blv,
        const float* bnk, const float* bnv,
        unsigned short* Wk, unsigned short* Wv, unsigned short* Wt1,
        unsigned short* Wnow, unsigned short* Wq, unsigned short* Wkk,
        unsigned short* Wvv, float* bck, float* bcv, float* bcn) {
    int i = blockIdx.x * 256 + threadIdx.x;
    if      (i < 16384)  Wk[i] = cvb(pk[i]);
    else if (i < 32768)  Wk[i] = cvb(lk[i - 16384]);
    else if (i < 49152)  Wv[i - 32768] = cvb(pv[i - 32768]);
    else if (i < 65536)  Wv[i - 32768] = cvb(lv[i - 49152]);
    else if (i < 98304)  Wt1[i - 65536] = cvb(t1[i - 65536]);
    else if (i < 114688) Wnow[i - 98304] = cvb(nk[i - 98304]);
    else if (i < 131072) Wnow[i - 98304] = cvb(nv[i - 114688]);
    else if (i < 147456) Wq[i - 131072] = cvb(q[i - 131072]);
    else if (i < 163840) Wkk[i - 147456] = cvb(k[i - 147456]);
    else if (i < 180224) Wvv[i - 163840] = cvb(v[i - 163840]);
    else if (i < 180480) { int j = i - 180224; bck[j] = j < 128 ? bpk[j] : blk[j - 128]; }
    else if (i < 180736) { int j = i - 180480; bcv[j] = j < 128 ? bpv[j] : blv[j - 128]; }
    else if (i < 180992) { int j = i - 180736; bcn[j] = j < 128 ? bnk[j] : bnv[j - 128]; }
}

// ============ fused pixelwise conv chain ============
// LDS activations in (n, ch) bf16, byte addr = n*rowB + (chByte ^ SWZ(n)).
// MFMA: A = activation rows (n), B = W^T cols (m) read from global bf16 W (M,K) row-major.

template<int KSTEPS, int ROWB>
__device__ __forceinline__ f32x16 gtile(const char* Ab, int aChBase,
        const unsigned short* W, int Wld, int wrow0, int nsub, int nl, int h) {
    f32x16 acc;
    #pragma unroll
    for (int r = 0; r < 16; ++r) acc[r] = 0.f;
    int n = nsub * 32 + nl;
    const char* arow = Ab + n * ROWB;
    const unsigned short* wrow = W + (size_t)(wrow0 + nl) * Wld + h * 8;
    #pragma unroll
    for (int kk = 0; kk < KSTEPS; ++kk) {
        bf16x8 a = *(const bf16x8*)(arow + ((aChBase + kk * 32 + h * 16) ^ SWZ(n)));
        bf16x8 wf = *(const bf16x8*)(wrow + kk * 16);
        acc = __builtin_amdgcn_mfma_f32_32x32x16_bf16(a, wf, acc, 0, 0, 0);
    }
    return acc;
}

__device__ __forceinline__ void epi_lds(char* dst, int rowB, f32x16 acc,
        const float* bias, int m0, int nsub, int nl, int h) {
    int m = m0 + nl;
    float bs = bias[m];
    #pragma unroll
    for (int r = 0; r < 16; ++r) {
        int n = nsub * 32 + (r & 3) + 8 * (r >> 2) + 4 * h;
        *(unsigned short*)(dst + n * rowB + ((m * 2) ^ SWZ(n))) =
            cvb(fmaxf(acc[r] + bs, 0.f));
    }
}

__device__ __forceinline__ void epi_nc(unsigned short* Y, f32x16 acc,
        const float* bias, int m0, int nsub, int n0g, int b, int nl, int h) {
    int m = m0 + nl;
    float bs = bias[m];
    #pragma unroll
    for (int r = 0; r < 16; ++r) {
        int n = nsub * 32 + (r & 3) + 8 * (r >> 2) + 4 * h;
        Y[((size_t)b * N_ + n0g + n) * C_ + m] = cvb(fmaxf(acc[r] + bs, 0.f));
    }
}

__device__ __forceinline__ void epi_cn_b16(unsigned short* Y, f32x16 acc,
        const float* bias, int m0, int nsub, int n0g, int b, int nl, int h) {
    int m = m0 + nl;
    float bs = bias[m];
    #pragma unroll
    for (int r2 = 0; r2 < 4; ++r2) {
        int nn = nsub * 32 + 8 * r2 + 4 * h;
        uint2 o;
        o.x = pk2(fmaxf(acc[4*r2+0] + bs, 0.f), fmaxf(acc[4*r2+1] + bs, 0.f));
        o.y = pk2(fmaxf(acc[4*r2+2] + bs, 0.f), fmaxf(acc[4*r2+3] + bs, 0.f));
        *(uint2*)(Y + ((size_t)b * C_ + m) * N_ + n0g + nn) = o;
    }
}

__device__ __forceinline__ void epi_cn_f32(float* Y, f32x16 acc,
        const float* bias, int m0, int nsub, int n0g, int b, int nl, int h) {
    int m = m0 + nl;
    float bs = bias[m];
    #pragma unroll
    for (int r2 = 0; r2 < 4; ++r2) {
        int nn = nsub * 32 + 8 * r2 + 4 * h;
        float4 o;
        o.x = fmaxf(acc[4*r2+0] + bs, 0.f);
        o.y = fmaxf(acc[4*r2+1] + bs, 0.f);
        o.z = fmaxf(acc[4*r2+2] + bs, 0.f);
        o.w = fmaxf(acc[4*r2+3] + bs, 0.f);
        *(float4*)(Y + ((size_t)b * C_ + m) * N_ + n0g + nn) = o;
    }
}

__global__ __launch_bounds__(512) void k_chain(
        const float* __restrict__ ev, const float* __restrict__ w_nb,
        const float* __restrict__ b_nb, const float* __restrict__ w_n1,
        const float* __restrict__ b_n1,
        const unsigned short* __restrict__ Wk, const unsigned short* __restrict__ Wv,
        const unsigned short* __restrict__ Wt1, const unsigned short* __restrict__ Wnow,
        const unsigned short* __restrict__ Wq, const unsigned short* __restrict__ Wkk,
        const unsigned short* __restrict__ Wvv,
        const float* __restrict__ bck, const float* __restrict__ bcv,
        const float* __restrict__ bt1, const float* __restrict__ bcn,
        const float* __restrict__ bq, const float* __restrict__ bk,
        const float* __restrict__ bv,
        unsigned short* __restrict__ Qt, unsigned short* __restrict__ Kb,
        unsigned short* __restrict__ Vb, float* __restrict__ NowV) {
    __shared__ char lds[114688];
    char* NEIGH = lds;                 // 64 x 512B  (256 ch)  [dies after S2]
    char* KCAT  = lds + 32768;         // 64 x 512B            [dies after S3]
    char* VCAT  = lds + 65536;         // 64 x 512B            [dies after S3]
    char* NOWF  = lds + 98304;         // 64 x 256B  (128 ch)
    char* KEYN  = lds;                 // 64 x 256B  (over NEIGH)
    char* VALN  = lds + 16384;         // 64 x 256B  (over NEIGH)
    char* NOWK  = lds + 32768;         // 64 x 256B  (over KCAT)

    const int t = threadIdx.x, lane = t & 63, w = t >> 6;
    const int nl = lane & 31, h = lane >> 5;
    const int b = blockIdx.y;
    const int n0g = blockIdx.x * 64;

    // ---- S1: neigh (256ch, K=4) + nowf (128ch, K=2), VALU f32 ----
    {
        int n = t & 63, grp = t >> 6;
        const float* evb = ev + (size_t)b * 6 * N_ + n0g + n;
        float e0 = evb[0], e1 = evb[N_], e4 = evb[4*N_], e5 = evb[5*N_];
        float e2 = evb[2*N_], e3 = evb[3*N_];
        int och0 = grp * 32;
        #pragma unroll
        for (int i = 0; i < 32; i += 4) {
            float r_[4];
            #pragma unroll
            for (int j = 0; j < 4; ++j) {
                int o = och0 + i + j;
                float4 w4 = *(const float4*)(w_nb + o * 4);
                r_[j] = fmaxf(b_nb[o] + w4.x*e0 + w4.y*e1 + w4.z*e4 + w4.w*e5, 0.f);
            }
            uint2 val; val.x = pk2(r_[0], r_[1]); val.y = pk2(r_[2], r_[3]);
            *(uint2*)(NEIGH + n * 512 + (((och0 + i) * 2) ^ SWZ(n))) = val;
        }
        int o0 = grp * 16;
        #pragma unroll
        for (int i = 0; i < 16; i += 4) {
            float r_[4];
            #pragma unroll
            for (int j = 0; j < 4; ++j) {
                int o = o0 + i + j;
                float2 w2 = *(const float2*)(w_n1 + o * 2);
                r_[j] = fmaxf(b_n1[o] + w2.x*e2 + w2.y*e3, 0.f);
            }
            uint2 val; val.x = pk2(r_[0], r_[1]); val.y = pk2(r_[2], r_[3]);
            *(uint2*)(NOWF + n * 256 + (((o0 + i) * 2) ^ SWZ(n))) = val;
        }
    }
    __syncthreads();

    // ---- S2: kcat = [Wpk;Wlk] @ neigh_pro ; vcat = [Wpv;Wlv] @ neigh_lat ----
    {
        int nsub = w & 1, m0 = (w >> 1) * 32;
        f32x16 a0 = gtile<8, 512>(NEIGH, 0,   Wk, 128, m0,       nsub, nl, h);
        f32x16 a1 = gtile<8, 512>(NEIGH, 0,   Wk, 128, m0 + 128, nsub, nl, h);
        f32x16 a2 = gtile<8, 512>(NEIGH, 256, Wv, 128, m0,       nsub, nl, h);
        f32x16 a3 = gtile<8, 512>(NEIGH, 256, Wv, 128, m0 + 128, nsub, nl, h);
        epi_lds(KCAT, 512, a0, bck, m0,       nsub, nl, h);
        epi_lds(KCAT, 512, a1, bck, m0 + 128, nsub, nl, h);
        epi_lds(VCAT, 512, a2, bcv, m0,       nsub, nl, h);
        epi_lds(VCAT, 512, a3, bcv, m0 + 128, nsub, nl, h);
    }
    __syncthreads();

    // ---- S3: keyn = Wt1 @ kcat ; valn = Wt1 @ vcat  (K=256) ----
    {
        int nsub = w & 1, m0 = (w >> 1) * 32;
        f32x16 a0 = gtile<16, 512>(KCAT, 0, Wt1, 256, m0, nsub, nl, h);
        f32x16 a1 = gtile<16, 512>(VCAT, 0, Wt1, 256, m0, nsub, nl, h);
        epi_lds(KEYN, 256, a0, bt1, m0, nsub, nl, h);
        epi_lds(VALN, 256, a1, bt1, m0, nsub, nl, h);
    }
    __syncthreads();

    // ---- S5: nowk = Wnk @ nowf (LDS) ; nowv = Wnv @ nowf (global f32 (C,N)) ----
    {
        int nsub = w & 1, m0 = (w >> 1) * 32;
        f32x16 a0 = gtile<8, 256>(NOWF, 0, Wnow, 128, m0,       nsub, nl, h);
        f32x16 a1 = gtile<8, 256>(NOWF, 0, Wnow, 128, m0 + 128, nsub, nl, h);
        epi_lds(NOWK, 256, a0, bcn, m0, nsub, nl, h);
        epi_cn_f32(NowV, a1, bcn + 128, m0, nsub, n0g, b, nl, h);
    }
    __syncthreads();

    // ---- S6: q = Wq @ keyn -> Qt(N,C) ; k = Wk @ nowk -> Kb(N,C) ; v -> Vb(C,N) ----
    {
        int nsub = w & 1, m0 = (w >> 1) * 32;
        f32x16 aq = gtile<8, 256>(KEYN, 0, Wq,  128, m0, nsub, nl, h);
        f32x16 ak = gtile<8, 256>(NOWK, 0, Wkk, 128, m0, nsub, nl, h);
        f32x16 av = gtile<8, 256>(VALN, 0, Wvv, 128, m0, nsub, nl, h);
        epi_nc(Qt, aq, bq, m0, nsub, n0g, b, nl, h);
        epi_nc(Kb, ak, bk, m0, nsub, n0g, b, nl, h);
        epi_cn_b16(Vb, av, bv, m0, nsub, n0g, b, nl, h);
    }
}

// ---------------- MFMA flash attention + epilogue (unchanged from r2) -------
#define MT 32
#define NMT (N_ / MT)
#define SPLIT 4

__global__ __launch_bounds__(512, 2) void k_flash(
        const unsigned short* __restrict__ Qt, const unsigned short* __restrict__ Kt,
        const unsigned short* __restrict__ Vb, const float* __restrict__ NV,
        float* __restrict__ out) {
    __shared__ char stg[131072];
    __shared__ float cmb[2][SPLIT][2][32];
    const int t = threadIdx.x;
    const int lane = t & 63;
    const int w = t >> 6;
    const int nh = w & 1, mp = w >> 1;
    const int h = lane >> 5, nl = lane & 31;
    const int b = blockIdx.y;
    const int n0 = blockIdx.x * 64 + nh * 32;
    const size_t bo = (size_t)b * N_ * C_;

    bf16x8 qf[8];
    {
        const char* qb = (const char*)(Qt + bo);
        #pragma unroll
        for (int kk = 0; kk < 8; ++kk)
            qf[kk] = *(const bf16x8*)(qb + (size_t)(n0 + nl) * 256 + kk*32 + h*16);
    }

    const char* ktb = (const char*)(Kt + bo);
    const char* vbb = (const char*)(Vb + bo);

    f32x16 oa[4];
    #pragma unroll
    for (int s = 0; s < 4; ++s)
        #pragma unroll
        for (int r = 0; r < 16; ++r) oa[s][r] = 0.f;
    float m_run = -1e30f, l_run = 0.f;

    const int swzK = (nl & 15) << 4;
    const int swzV = ((nl >> 1) & 7) << 4;

    auto stage = [&](int tile, int ph) {
        char* base = stg + (mp*2 + ph) * 16384;
        if (nh == 0) {
            const char* src = ktb + (size_t)tile * MT * 256;
            #pragma unroll
            for (int ii = 0; ii < 8; ++ii) {
                int L = ii*1024 + lane*16;
                int T = L ^ (((L >> 8) & 15) << 4);
                gload_lds16(src + T, base + ii*1024);
            }
        } else {
            const char* src = vbb + (size_t)tile * MT * 2;
            #pragma unroll
            for (int ii = 0; ii < 8; ++ii) {
                int L = ii*1024 + lane*16;
                int T = L ^ (((L >> 7) & 7) << 4);
                int c = T >> 6, inner = T & 63;
                gload_lds16(src + (size_t)c * (N_*2) + inner, base + 8192 + ii*1024);
            }
        }
    };

    stage(mp, 0);
    asm volatile("s_waitcnt vmcnt(0)" ::: "memory");
    __syncthreads();

    for (int it = 0; it < NMT / SPLIT; ++it) {
        int ph = it & 1;
        if (it + 1 < NMT / SPLIT) stage((it + 1) * SPLIT + mp, ph ^ 1);
        const char* kb = stg + (mp*2 + ph) * 16384;
        const char* vb = kb + 8192;

        f32x16 s;
        #pragma unroll
        for (int r = 0; r < 16; ++r) s[r] = 0.f;
        #pragma unroll
        for (int kk = 0; kk < 8; ++kk) {
            int y = nl*256 + kk*32 + h*16;
            bf16x8 a = *(const bf16x8*)(kb + (y ^ swzK));
            s = __builtin_amdgcn_mfma_f32_32x32x16_bf16(a, qf[kk], s, 0, 0, 0);
        }

        float tm = -1e30f;
        #pragma unroll
        for (int r = 0; r < 16; ++r) tm = fmaxf(tm, s[r]);
        tm = fmaxf(tm, __shfl_xor(tm, 32));
        float mn = fmaxf(m_run, tm);
        float sc = __expf(m_run - mn);
        m_run = mn;
        float p[16];
        float ls = 0.f;
        #pragma unroll
        for (int r = 0; r < 16; ++r) { p[r] = __expf(s[r] - mn); ls += p[r]; }
        ls += __shfl_xor(ls, 32);
        l_run = l_run * sc + ls;
        #pragma unroll
        for (int ss = 0; ss < 4; ++ss)
            #pragma unroll
            for (int r = 0; r < 16; ++r) oa[ss][r] *= sc;

        unsigned pk[8], opk[8];
        #pragma unroll
        for (int q = 0; q < 8; ++q) pk[q] = pk2(p[2*q], p[2*q+1]);
        #pragma unroll
        for (int q = 0; q < 8; ++q) opk[q] = (unsigned)__shfl_xor((int)pk[q], 32);

        #pragma unroll
        for (int kk2 = 0; kk2 < 2; ++kk2) {
            unsigned w0 = h ? opk[4*kk2+2] : pk [4*kk2+0];
            unsigned w1 = h ? opk[4*kk2+3] : pk [4*kk2+1];
            unsigned w2 = h ? pk [4*kk2+2] : opk[4*kk2+0];
            unsigned w3 = h ? pk [4*kk2+3] : opk[4*kk2+1];
            typedef __attribute__((ext_vector_type(4))) unsigned u32x4;
            u32x4 uw = {w0, w1, w2, w3};
            bf16x8 pf = __builtin_bit_cast(bf16x8, uw);
            #pragma unroll
            for (int ss = 0; ss < 4; ++ss) {
                int y = (32*ss + nl)*64 + kk2*32 + h*16;
                bf16x8 va = *(const bf16x8*)(vb + (y ^ swzV));
                oa[ss] = __builtin_amdgcn_mfma_f32_32x32x16_bf16(va, pf, oa[ss], 0, 0, 0);
            }
        }

        asm volatile("s_waitcnt vmcnt(0)" ::: "memory");
        __syncthreads();
    }

    if (h == 0) { cmb[nh][mp][0][nl] = m_run; cmb[nh][mp][1][nl] = l_run; }
    __syncthreads();
    float M = -1e30f;
    #pragma unroll
    for (int j = 0; j < SPLIT; ++j) M = fmaxf(M, cmb[nh][j][0][nl]);
    float lt = 0.f;
    #pragma unroll
    for (int j = 0; j < SPLIT; ++j) lt += cmb[nh][j][1][nl] * __expf(cmb[nh][j][0][nl] - M);
    float aw = __expf(m_run - M);
    float* osc = (float*)stg;
    if (mp != 0) {
        float* dst = osc + (size_t)((mp-1)*2 + nh) * 4096;
        #pragma unroll
        for (int ss = 0; ss < 4; ++ss)
            #pragma unroll
            for (int r = 0; r < 16; ++r) {
                int c = 32*ss + (r&3) + 8*(r>>2) + 4*h;
                dst[c*32 + nl] = oa[ss][r] * aw;
            }
    }
    __syncthreads();
    if (mp == 0) {
        const float* nvb = NV + bo;
        float* ob = out + bo;
        float inv = 1.f / lt;
        #pragma unroll
        for (int ss = 0; ss < 4; ++ss)
            #pragma unroll
            for (int r = 0; r < 16; ++r) {
                int c = 32*ss + (r&3) + 8*(r>>2) + 4*h;
                float v = oa[ss][r] * aw;
                v += osc[(0*2+nh)*4096 + c*32 + nl];
                v += osc[(1*2+nh)*4096 + c*32 + nl];
                v += osc[(2*2+nh)*4096 + c*32 + nl];
                size_t gi = (size_t)c * N_ + blockIdx.x*64 + nh*32 + nl;
                ob[gi] = 1e-4f * (v * inv) + nvb[gi];
            }
    }
}

extern "C" void kernel_launch(void* const* d_in, const int* in_sizes, int n_in,
                              void* d_out, int out_size, void* d_ws, size_t ws_size,
                              hipStream_t stream) {
    const float* ev   = (const float*)d_in[0];
    const float* w_nb = (const float*)d_in[1];  const float* b_nb = (const float*)d_in[2];
    const float* w_pk = (const float*)d_in[3];  const float* b_pk = (const float*)d_in[4];
    const float* w_pv = (const float*)d_in[5];  const float* b_pv = (const float*)d_in[6];
    const float* w_lk = (const float*)d_in[7];  const float* b_lk = (const float*)d_in[8];
    const float* w_lv = (const float*)d_in[9];  const float* b_lv = (const float*)d_in[10];
    const float* w_t1 = (const float*)d_in[11]; const float* b_t1 = (const float*)d_in[12];
    const float* w_n1 = (const float*)d_in[13]; const float* b_n1 = (const float*)d_in[14];
    const float* w_nk = (const float*)d_in[15]; const float* b_nk = (const float*)d_in[16];
    const float* w_nv = (const float*)d_in[17]; const float* b_nv = (const float*)d_in[18];
    const float* w_q  = (const float*)d_in[19]; const float* b_q  = (const float*)d_in[20];
    const float* w_k  = (const float*)d_in[21]; const float* b_k  = (const float*)d_in[22];
    const float* w_v  = (const float*)d_in[23]; const float* b_v  = (const float*)d_in[24];

    char* p = (char*)d_ws;
    unsigned short* Qt = (unsigned short*)p; p += (size_t)B_*N_*C_*2;   // 4 MB
    unsigned short* Kb = (unsigned short*)p; p += (size_t)B_*N_*C_*2;   // 4 MB
    unsigned short* Vb = (unsigned short*)p; p += (size_t)B_*C_*N_*2;   // 4 MB
    float*          NowV = (float*)p;        p += (size_t)B_*C_*N_*4;   // 8 MB
    unsigned short* Wk   = (unsigned short*)p; p += 32768*2;
    unsigned short* Wv   = (unsigned short*)p; p += 32768*2;
    unsigned short* Wt1  = (unsigned short*)p; p += 32768*2;
    unsigned short* Wnow = (unsigned short*)p; p += 32768*2;
    unsigned short* Wq   = (unsigned short*)p; p += 16384*2;
    unsigned short* Wkk  = (unsigned short*)p; p += 16384*2;
    unsigned short* Wvv  = (unsigned short*)p; p += 16384*2;
    float* bck = (float*)p; p += 256*4;
    float* bcv = (float*)p; p += 256*4;
    float* bcn = (float*)p; p += 256*4;

    k_wcvt<<<dim3(707), dim3(256), 0, stream>>>(
        w_pk, w_lk, w_pv, w_lv, w_t1, w_nk, w_nv, w_q, w_k, w_v,
        b_pk, b_lk, b_pv, b_lv, b_nk, b_nv,
        Wk, Wv, Wt1, Wnow, Wq, Wkk, Wvv, bck, bcv, bcn);

    k_chain<<<dim3(N_/64, B_), dim3(512), 0, stream>>>(
        ev, w_nb, b_nb, w_n1, b_n1,
        Wk, Wv, Wt1, Wnow, Wq, Wkk, Wvv,
        bck, bcv, b_t1, bcn, b_q, b_k, b_v,
        Qt, Kb, Vb, NowV);

    k_flash<<<dim3(N_/64, B_), dim3(512), 0, stream>>>(Qt, Kb, Vb, NowV, (float*)d_out);
}